// Round 8
// baseline (248.011 us; speedup 1.0000x reference)
//
#include <hip/hip_runtime.h>
#include <hip/hip_bf16.h>

typedef __attribute__((ext_vector_type(8))) short bf16x8;
typedef __attribute__((ext_vector_type(4))) float f32x4;
typedef __attribute__((ext_vector_type(16))) float f32x16;
typedef __attribute__((ext_vector_type(4))) short short4v;
typedef __attribute__((ext_vector_type(4))) unsigned u32x4;

__device__ __forceinline__ unsigned short f2bf(float f) {
  union { float f; unsigned u; } x; x.f = f;
  return (unsigned short)((x.u + 0x7FFFu + ((x.u >> 16) & 1u)) >> 16);
}

__device__ __forceinline__ short f2bf_hw(float f) {
  __hip_bfloat16 h = __float2bfloat16(f);
  return *(short*)&h;
}

__device__ __forceinline__ unsigned pk2(float a, float b) {
  float2 t2; t2.x = a; t2.y = b;
  __hip_bfloat162 t = __float22bfloat162_rn(t2);
  return *(unsigned*)&t;
}

__device__ __forceinline__ void lds_cp16(const void* g, void* l) {
  __builtin_amdgcn_global_load_lds(
      (const __attribute__((address_space(1))) void*)g,
      (__attribute__((address_space(3))) void*)l,
      16, 0, 0);
}

#define GBAR() do { __builtin_amdgcn_s_barrier(); __builtin_amdgcn_sched_barrier(0); } while (0)

// ---------------- cast fp32 -> bf16, vectorized ----------------
__global__ __launch_bounds__(256) void cast_x(const float* __restrict__ in,
                                              short* __restrict__ out, int n4) {
  int i = blockIdx.x * 256 + threadIdx.x;
  if (i >= n4) return;
  float4 v = reinterpret_cast<const float4*>(in)[i];
  short4v o;
  o.x = (short)f2bf(v.x); o.y = (short)f2bf(v.y);
  o.z = (short)f2bf(v.z); o.w = (short)f2bf(v.w);
  reinterpret_cast<short4v*>(out)[i] = o;
}

// ---------------- transpose + cast: in KxN fp32 -> out NxK bf16 ----------------
__global__ __launch_bounds__(256) void transp_cast(const float* __restrict__ in,
                                                   short* __restrict__ out,
                                                   int K, int N) {
  __shared__ float t[32][33];
  int bn = blockIdx.x * 32, bk = blockIdx.y * 32;
  int tx = threadIdx.x, ty = threadIdx.y;
  for (int i = ty; i < 32; i += 8)
    t[i][tx] = in[(size_t)(bk + i) * N + bn + tx];
  __syncthreads();
  for (int i = ty; i < 32; i += 8)
    out[(size_t)(bn + i) * K + bk + tx] = (short)f2bf(t[tx][i]);
}

// ---------------- bf16 transpose: per head [2048 pos][128 dh] -> [128 dh][2048 pos]
__global__ __launch_bounds__(256) void transp_v(const short* __restrict__ V,
                                                short* __restrict__ VTo) {
  __shared__ short t[32][34];
  const int hd = blockIdx.z;
  const int p0 = blockIdx.x * 32, d0 = blockIdx.y * 32;
  const short* src = V + (size_t)hd * 2048 * 128;
  short* dst = VTo + (size_t)hd * 2048 * 128;
  int tx = threadIdx.x, ty = threadIdx.y;
  for (int i = ty; i < 32; i += 8)
    t[i][tx] = src[(size_t)(p0 + i) * 128 + d0 + tx];
  __syncthreads();
  for (int i = ty; i < 32; i += 8)
    dst[(size_t)(d0 + i) * 2048 + p0 + tx] = t[tx][i];
}

// ---------------- 8-wave deep-phase GEMM (unchanged from round 6) ------------
template <int BM, int EPI>
__global__ __launch_bounds__(512, 2) void gemm8p(
    const short* __restrict__ A, const short* __restrict__ Bt,
    float* __restrict__ C,
    short* __restrict__ Qo, short* __restrict__ Ko, short* __restrict__ Vo,
    const float* __restrict__ cosT, const float* __restrict__ sinT,
    int N, int Kd, int nbm) {
  constexpr int NM = BM / 64;
  __shared__ __align__(16) short As[2][BM * 64];
  __shared__ __align__(16) short Bs[2][256 * 64];
  const int tid = threadIdx.x;
  const int l = tid & 63, l15 = l & 15, l4 = l >> 4;
  const int wid = tid >> 6, wr = wid >> 1, wc = wid & 1;
  const int cpx = gridDim.x >> 3;
  const int sid = (blockIdx.x & 7) * cpx + (blockIdx.x >> 3);
  const int bm = sid % nbm, bn = sid / nbm;

  const int srow = tid >> 3;
  const int sch = tid & 7;

  auto stA = [&](int dbuf, int k0, int i) {
    const int rl = srow + i * 64;
    const int c = sch ^ (rl & 7);
    lds_cp16(A + (size_t)(bm * BM + rl) * Kd + k0 + c * 8,
             (char*)As[dbuf] + tid * 16 + i * 8192);
  };
  auto stB = [&](int dbuf, int k0, int j) {
    const int rl = srow + j * 64;
    const int c = sch ^ (rl & 7);
    lds_cp16(Bt + (size_t)(bn * 256 + rl) * Kd + k0 + c * 8,
             (char*)Bs[dbuf] + tid * 16 + j * 8192);
  };
  auto rdA = [&](int dbuf, int m, int kb) {
    const int row = wr * (BM / 4) + m * 16 + l15;
    return *(const bf16x8*)((const char*)As[dbuf] + (row << 7) +
                            ((kb * 64 + l4 * 16) ^ ((row & 7) << 4)));
  };
  auto rdB = [&](int dbuf, int nh, int f, int kb) {
    const int row = wc * 128 + nh * 64 + f * 16 + l15;
    return *(const bf16x8*)((const char*)Bs[dbuf] + (row << 7) +
                            ((kb * 64 + l4 * 16) ^ ((row & 7) << 4)));
  };

  f32x4 acc[NM][8];
#pragma unroll
  for (int m = 0; m < NM; m++)
#pragma unroll
    for (int n = 0; n < 8; n++) acc[m][n] = (f32x4){0.f, 0.f, 0.f, 0.f};

  const int NT = Kd >> 6;

#pragma unroll
  for (int i = 0; i < NM; i++) stA(0, 0, i);
#pragma unroll
  for (int j = 0; j < 4; j++) stB(0, 0, j);
  asm volatile("s_waitcnt vmcnt(0)" ::: "memory");
  GBAR();

  for (int kt = 0; kt < NT; kt++) {
    const int buf = kt & 1, nbf = buf ^ 1;
    const bool stg = (kt + 1 < NT);
    const int k1 = (kt + 1) << 6;
    bf16x8 a[NM], b[4];

    // ---------- phase 0 ----------
#pragma unroll
    for (int m = 0; m < NM; m++) a[m] = rdA(buf, m, 0);
#pragma unroll
    for (int f = 0; f < 4; f++) b[f] = rdB(buf, 0, f, 0);
    if (stg) { stA(nbf, k1, 0); stA(nbf, k1, 1); }
    if (stg) asm volatile("s_waitcnt vmcnt(2)" ::: "memory");
    else     asm volatile("s_waitcnt vmcnt(0)" ::: "memory");
    GBAR();
    asm volatile("s_waitcnt lgkmcnt(0)" ::: "memory");
    __builtin_amdgcn_sched_barrier(0);
    __builtin_amdgcn_s_setprio(1);
#pragma unroll
    for (int m = 0; m < NM; m++)
#pragma unroll
      for (int f = 0; f < 4; f++)
        acc[m][f] = __builtin_amdgcn_mfma_f32_16x16x32_bf16(a[m], b[f], acc[m][f], 0, 0, 0);
    __builtin_amdgcn_s_setprio(0);
    GBAR();

    // ---------- phase 1 ----------
#pragma unroll
    for (int f = 0; f < 4; f++) b[f] = rdB(buf, 1, f, 0);
    if (stg) {
      if (BM == 256) { stA(nbf, k1, 2); stA(nbf, k1, 3); }
      else           { stB(nbf, k1, 0); stB(nbf, k1, 2); }
    }
    GBAR();
    asm volatile("s_waitcnt lgkmcnt(0)" ::: "memory");
    __builtin_amdgcn_sched_barrier(0);
    __builtin_amdgcn_s_setprio(1);
#pragma unroll
    for (int m = 0; m < NM; m++)
#pragma unroll
      for (int f = 0; f < 4; f++)
        acc[m][4 + f] = __builtin_amdgcn_mfma_f32_16x16x32_bf16(a[m], b[f], acc[m][4 + f], 0, 0, 0);
    __builtin_amdgcn_s_setprio(0);
    GBAR();

    // ---------- phase 2 ----------
#pragma unroll
    for (int m = 0; m < NM; m++) a[m] = rdA(buf, m, 1);
#pragma unroll
    for (int f = 0; f < 4; f++) b[f] = rdB(buf, 0, f, 1);
    if (stg) {
      if (BM == 256) { stB(nbf, k1, 0); stB(nbf, k1, 2); }
      else           { stB(nbf, k1, 1); stB(nbf, k1, 3); }
    }
    GBAR();
    asm volatile("s_waitcnt lgkmcnt(0)" ::: "memory");
    __builtin_amdgcn_sched_barrier(0);
    __builtin_amdgcn_s_setprio(1);
#pragma unroll
    for (int m = 0; m < NM; m++)
#pragma unroll
      for (int f = 0; f < 4; f++)
        acc[m][f] = __builtin_amdgcn_mfma_f32_16x16x32_bf16(a[m], b[f], acc[m][f], 0, 0, 0);
    __builtin_amdgcn_s_setprio(0);
    GBAR();

    // ---------- phase 3 ----------
#pragma unroll
    for (int f = 0; f < 4; f++) b[f] = rdB(buf, 1, f, 1);
    if (stg && BM == 256) { stB(nbf, k1, 1); stB(nbf, k1, 3); }
    if (stg) asm volatile("s_waitcnt vmcnt(2)" ::: "memory");
    GBAR();
    asm volatile("s_waitcnt lgkmcnt(0)" ::: "memory");
    __builtin_amdgcn_sched_barrier(0);
    __builtin_amdgcn_s_setprio(1);
#pragma unroll
    for (int m = 0; m < NM; m++)
#pragma unroll
      for (int f = 0; f < 4; f++)
        acc[m][4 + f] = __builtin_amdgcn_mfma_f32_16x16x32_bf16(a[m], b[f], acc[m][4 + f], 0, 0, 0);
    __builtin_amdgcn_s_setprio(0);
    GBAR();
  }

  if (EPI == 0) {
#pragma unroll
    for (int m = 0; m < NM; m++) {
      const int grow = bm * BM + wr * (BM / 4) + m * 16 + l4 * 4;
#pragma unroll
      for (int ni = 0; ni < 8; ni++) {
        const int col = bn * 256 + wc * 128 + (ni >> 2) * 64 + (ni & 3) * 16 + l15;
#pragma unroll
        for (int r = 0; r < 4; r++)
          C[(size_t)(grow + r) * N + col] = acc[m][ni][r];
      }
    }
  } else {
    const int head = bn * 2 + wc;
#pragma unroll
    for (int m = 0; m < NM; m++) {
#pragma unroll
      for (int r = 0; r < 4; r++) {
        const int grow = bm * BM + wr * (BM / 4) + m * 16 + l4 * 4 + r;
        const int bb = grow >> 11, pos = grow & 2047;
        if (head < 20) {
          float c4[4], s4[4];
#pragma unroll
          for (int ni = 0; ni < 4; ni++) {
            const int dh = ni * 16 + l15;
            c4[ni] = cosT[pos * 128 + dh];
            s4[ni] = sinT[pos * 128 + dh];
          }
          short* dst;
          if (head < 16) dst = Qo + ((size_t)(bb * 16 + head) * 2048 + pos) * 128;
          else           dst = Ko + ((size_t)(bb * 4 + (head - 16)) * 2048 + pos) * 128;
#pragma unroll
          for (int ni = 0; ni < 4; ni++) {
            const int dh = ni * 16 + l15;
            float xlo = acc[m][ni][r], xhi = acc[m][ni + 4][r];
            dst[dh]      = (short)f2bf(xlo * c4[ni] - xhi * s4[ni]);
            dst[dh + 64] = (short)f2bf(xhi * c4[ni] + xlo * s4[ni]);
          }
        } else {
          short* dst = Vo + ((size_t)(bb * 4 + (head - 20)) * 2048 + pos) * 128;
#pragma unroll
          for (int ni = 0; ni < 8; ni++)
            dst[(ni >> 2) * 64 + (ni & 3) * 16 + l15] = (short)f2bf(acc[m][ni][r]);
        }
      }
    }
  }
}

// ---------------- flash attention, causal, GQA — 32x32 MFMA, in-reg P -------
// 512 blocks x 2 waves (32q each). Block owns uniform pair (pp, 31-pp):
// 33 kv-tiles of 64 keys. Swapped QK^T (mfma(K,Q)) puts q in C cols, so each
// lane holds P for one q-row; P->A-frag via packed bf16 cvt + half-shuffle
// (no LDS round trip). K/V^T dbuf-staged via global_load_lds (pre-swizzled
// source, XOR (row&7)<<4). No-max softmax; l via ones-MFMA. XCD chunking:
// 64-block chunk = one kv-group (K+V 1MB L2-resident).
__global__ __launch_bounds__(128) void attn_fwd(
    const short* __restrict__ Q, const short* __restrict__ K,
    const short* __restrict__ VT, short* __restrict__ AO) {
  __shared__ __align__(16) short Ks[2][64 * 128];
  __shared__ __align__(16) short VTs[2][128 * 64];
  const int tid = threadIdx.x;
  const int w = tid >> 6, l = tid & 63;
  const int l31 = l & 31, hi = l >> 5;
  const int bid = blockIdx.x;
  const int lg = (bid & 7) * 64 + (bid >> 3);   // XCD-chunked logical id
  const int bh = lg >> 4, pp = lg & 15;
  const int b = bh >> 4, h = bh & 15, kv = h >> 2;
  const short* Qbase = Q + (size_t)(b * 16 + h) * 2048 * 128;
  const short* Kbase = K + (size_t)(b * 4 + kv) * 2048 * 128;
  const short* VTb   = VT + (size_t)(b * 4 + kv) * 2048 * 128;

  // staging: K = 64 rows x 16 chunks, V^T = 128 rows x 8 chunks; 8 cp16/thread
  // each; pre-swizzled source chunk so LDS stays linear (swizzle on read).
  int koff[8], voff[8];
#pragma unroll
  for (int i = 0; i < 8; i++) {
    const int c = tid + i * 128;
    const int rk = c >> 4, ck = (c & 15) ^ (rk & 7);
    const int dv = c >> 3, kc = (c & 7) ^ (dv & 7);
    koff[i] = rk * 128 + ck * 8;
    voff[i] = dv * 2048 + kc * 8;
  }

  const float SCL = 0.08838834764831845f * 1.4426950408889634f;  // 1/sqrt(128)*log2e
  bf16x8 ones;
#pragma unroll
  for (int j = 0; j < 8; j++) ones[j] = (short)0x3F80;

  for (int qq = 0; qq < 2; qq++) {
    const int qt = qq ? (31 - pp) : pp;
    const int q0w = qt * 64 + w * 32;

    // Q fragments: row = q0w + l31, depth d = kb*16 + hi*8
    bf16x8 qf[8];
#pragma unroll
    for (int kb = 0; kb < 8; kb++)
      qf[kb] = *(const bf16x8*)(Qbase + (size_t)(q0w + l31) * 128 + kb * 16 + hi * 8);

    f32x16 oacc[4];
#pragma unroll
    for (int nb = 0; nb < 4; nb++)
#pragma unroll
      for (int r = 0; r < 16; r++) oacc[nb][r] = 0.f;
    f32x16 lacc;
#pragma unroll
    for (int r = 0; r < 16; r++) lacc[r] = 0.f;

    const int ntiles = qt + 1;

    __syncthreads();  // prior q-tile's LDS reads complete before restaging
#pragma unroll
    for (int i = 0; i < 8; i++) {
      lds_cp16(Kbase + koff[i], (char*)Ks[0] + i * 2048 + tid * 16);
      lds_cp16(VTb + voff[i],   (char*)VTs[0] + i * 2048 + tid * 16);
    }

    for (int nt = 0; nt < ntiles; nt++) {
      const int k0 = nt * 64, buf = nt & 1;
      __syncthreads();  // drains own vmcnt -> tile nt resident for all waves
      if (nt + 1 < ntiles) {
        const int kn = k0 + 64, bnx = buf ^ 1;
#pragma unroll
        for (int i = 0; i < 8; i++) {
          lds_cp16(Kbase + (size_t)kn * 128 + koff[i], (char*)Ks[bnx] + i * 2048 + tid * 16);
          lds_cp16(VTb + kn + voff[i],                 (char*)VTs[bnx] + i * 2048 + tid * 16);
        }
      }

      // S^T = K @ Q^T (swapped): sa[kg] C-layout: col = q = l31,
      // row = key_local = (r&3)+8*(r>>2)+4*hi
      f32x16 sa[2];
#pragma unroll
      for (int r = 0; r < 16; r++) { sa[0][r] = 0.f; sa[1][r] = 0.f; }
      __builtin_amdgcn_s_setprio(1);
#pragma unroll
      for (int kg = 0; kg < 2; kg++) {
        const int row = kg * 32 + l31;
        const int swz = (row & 7) << 4;
#pragma unroll
        for (int kb = 0; kb < 8; kb++) {
          const char* kp = (const char*)Ks[buf] + row * 256 + ((kb * 32 + hi * 16) ^ swz);
          sa[kg] = __builtin_amdgcn_mfma_f32_32x32x16_bf16(*(const bf16x8*)kp, qf[kb], sa[kg], 0, 0, 0);
        }
      }
      __builtin_amdgcn_s_setprio(0);

      // P = exp(s*scale) in place; mask only the diagonal tile
      const bool domask = (k0 + 63 > q0w);
      const int qrow = q0w + l31;
#pragma unroll
      for (int kg = 0; kg < 2; kg++)
#pragma unroll
        for (int r = 0; r < 16; r++) {
          float pv = exp2f(sa[kg][r] * SCL);
          if (domask) {
            const int key = k0 + kg * 32 + (r & 3) + 8 * (r >> 2) + 4 * hi;
            if (key > qrow) pv = 0.f;
          }
          sa[kg][r] = pv;
        }

      // P -> A-fragments in registers: 4 pk-cvts + 2 half-shuffles per ks.
      // My regs r0..r0+3 hold keys ks*16+4*hi+{0..3}; r0+4..7 hold +8 more.
      bf16x8 pa[4];
#pragma unroll
      for (int ks = 0; ks < 4; ks++) {
        const int kg = ks >> 1, r0 = (ks & 1) * 8;
        unsigned X = pk2(sa[kg][r0 + 0], sa[kg][r0 + 1]);
        unsigned Y = pk2(sa[kg][r0 + 2], sa[kg][r0 + 3]);
        unsigned Z = pk2(sa[kg][r0 + 4], sa[kg][r0 + 5]);
        unsigned W = pk2(sa[kg][r0 + 6], sa[kg][r0 + 7]);
        unsigned s0 = hi ? X : Z, s1 = hi ? Y : W;
        unsigned g0 = (unsigned)__shfl((int)s0, l ^ 32);
        unsigned g1 = (unsigned)__shfl((int)s1, l ^ 32);
        u32x4 pw;
        pw.x = hi ? g0 : X;
        pw.y = hi ? g1 : Y;
        pw.z = hi ? Z : g0;
        pw.w = hi ? W : g1;
        pa[ks] = *(bf16x8*)&pw;
      }

      // O += P @ V^T ; l += P @ ones
      __builtin_amdgcn_s_setprio(1);
#pragma unroll
      for (int nb = 0; nb < 4; nb++) {
        const int row = nb * 32 + l31;
        const int swz = (row & 7) << 4;
#pragma unroll
        for (int ks = 0; ks < 4; ks++) {
          const char* vp = (const char*)VTs[buf] + row * 128 + ((ks * 32 + hi * 16) ^ swz);
          oacc[nb] = __builtin_amdgcn_mfma_f32_32x32x16_bf16(pa[ks], *(const bf16x8*)vp, oacc[nb], 0, 0, 0);
        }
      }
#pragma unroll
      for (int ks = 0; ks < 4; ks++)
        lacc = __builtin_amdgcn_mfma_f32_32x32x16_bf16(pa[ks], ones, lacc, 0, 0, 0);
      __builtin_amdgcn_s_setprio(0);
    }

    // epilogue: rows = q (same crow formula for oacc and lacc), cols = d
#pragma unroll
    for (int r = 0; r < 16; r++) {
      const float inv = 1.0f / lacc[r];
      const int q = q0w + (r & 3) + 8 * (r >> 2) + 4 * hi;
      const size_t rowb = ((size_t)b * 2048 + q) * 2048 + h * 128;
#pragma unroll
      for (int nb = 0; nb < 4; nb++)
        AO[rowb + nb * 32 + l31] = f2bf_hw(oacc[nb][r] * inv);
    }
  }
}

extern "C" void kernel_launch(void* const* d_in, const int* in_sizes, int n_in,
                              void* d_out, int out_size, void* d_ws, size_t ws_size,
                              hipStream_t stream) {
  const float* hs   = (const float*)d_in[0];
  const float* cosT = (const float*)d_in[1];
  const float* sinT = (const float*)d_in[2];
  const float* Wq   = (const float*)d_in[3];
  const float* Wk   = (const float*)d_in[4];
  const float* Wv   = (const float*)d_in[5];
  const float* Wo   = (const float*)d_in[6];
  float* out = (float*)d_out;

  char* p = (char*)d_ws;
  short* Xb   = (short*)p; p += (size_t)4096 * 2048 * 2;   // reused as AO
  short* Wqkv = (short*)p; p += (size_t)3072 * 2048 * 2;
  short* Wot  = (short*)p; p += (size_t)2048 * 2048 * 2;
  short* Qb   = (short*)p; p += (size_t)2 * 16 * 2048 * 128 * 2;
  short* Kb   = (short*)p; p += (size_t)2 * 4 * 2048 * 128 * 2;
  short* Vb   = (short*)p; p += (size_t)2 * 4 * 2048 * 128 * 2;
  short* VTb  = (short*)p; p += (size_t)2 * 4 * 2048 * 128 * 2;
  short* AO   = Xb;

  cast_x<<<8192, 256, 0, stream>>>(hs, Xb, 2097152);
  transp_cast<<<dim3(64, 64), dim3(32, 8), 0, stream>>>(Wq, Wqkv, 2048, 2048);
  transp_cast<<<dim3(16, 64), dim3(32, 8), 0, stream>>>(Wk, Wqkv + (size_t)2048 * 2048, 2048, 512);
  transp_cast<<<dim3(16, 64), dim3(32, 8), 0, stream>>>(Wv, Wqkv + (size_t)2560 * 2048, 2048, 512);
  transp_cast<<<dim3(64, 64), dim3(32, 8), 0, stream>>>(Wo, Wot, 2048, 2048);

  // QKV: M=4096, N=3072 -> 192 blocks, fused RoPE epilogue
  gemm8p<256, 1><<<192, 512, 0, stream>>>(Xb, Wqkv, nullptr, Qb, Kb, Vb,
                                          cosT, sinT, 3072, 2048, 16);
  transp_v<<<dim3(64, 4, 8), dim3(32, 8), 0, stream>>>(Vb, VTb);
  attn_fwd<<<512, 128, 0, stream>>>(Qb, Kb, VTb, AO);
  // out-proj: M=4096, N=2048 -> 256 blocks
  gemm8p<128, 0><<<256, 512, 0, stream>>>(AO, Wot, out, nullptr, nullptr, nullptr,
                                          nullptr, nullptr, 2048, 2048, 32);
}